// Round 3
// baseline (1250.516 us; speedup 1.0000x reference)
//
#include <hip/hip_runtime.h>
#include <math.h>

#define HDIM 768
#define BDIM 256
#define INDIM 64
#define NLAYERS 4
#define PDIM 8
#define KSPLIT 10     // 8 slots x 80k + 2 slots x 64k = 768
#define CHK 16        // k per LDS chunk
#define TR 128        // rows per block tile
#define TC 64         // cols per block tile

__device__ __forceinline__ float sigmoidf_(float x) { return 1.f / (1.f + expf(-x)); }
__device__ __forceinline__ float geluf_(float x) { return 0.5f * x * (1.f + erff(x * 0.70710678118654752f)); }

// async global->LDS, 16B/lane, lane i lands at ldsbase + i*16 (wave-uniform base)
__device__ __forceinline__ void gload_lds16(const float* g, float* l) {
    __builtin_amdgcn_global_load_lds((const __attribute__((address_space(1))) void*)g,
                                     (__attribute__((address_space(3))) void*)l, 16, 0, 0);
}

// ---------------------------------------------------------------------------
// Transpose trop_w [L][o][i] -> twT [L][i][o].  grid (12,12,L), 256 thr.
// ---------------------------------------------------------------------------
__global__ __launch_bounds__(256) void transpose_w_k(const float* __restrict__ src,
                                                     float* __restrict__ dst)
{
    __shared__ float tile[64][65];
    const int l = blockIdx.z;
    const int o0 = blockIdx.x * 64;
    const int i0 = blockIdx.y * 64;
    const int c = threadIdx.x & 63;
    const int r4 = threadIdx.x >> 6;
    const float* s = src + (size_t)l * HDIM * HDIM;
    float* d = dst + (size_t)l * HDIM * HDIM;
#pragma unroll
    for (int it = 0; it < 16; ++it) {
        const int r = it * 4 + r4;
        tile[r][c] = s[(size_t)(o0 + r) * HDIM + i0 + c];
    }
    __syncthreads();
#pragma unroll
    for (int it = 0; it < 16; ++it) {
        const int r = it * 4 + r4;
        d[(size_t)(i0 + r) * HDIM + o0 + c] = tile[c][r];
    }
}

// ---------------------------------------------------------------------------
// Kernel 0: h = x @ w_in + b_in, then LN(layer 0) -> hnT ([k][b] transposed).
// ---------------------------------------------------------------------------
__global__ __launch_bounds__(256) void input_ln_k(
    const float* __restrict__ x, const float* __restrict__ w_in,
    const float* __restrict__ b_in,
    const float* __restrict__ lng, const float* __restrict__ lnb,
    float* __restrict__ h, float* __restrict__ hnT)
{
    const int b = blockIdx.x;
    const int t = threadIdx.x;
    __shared__ float xs[INDIM];
    __shared__ float rbuf[8];
    if (t < INDIM) xs[t] = x[b * INDIM + t];
    __syncthreads();

    float acc0 = b_in[t], acc1 = b_in[t + 256], acc2 = b_in[t + 512];
#pragma unroll 8
    for (int i = 0; i < INDIM; ++i) {
        const float xv = xs[i];
        acc0 = fmaf(xv, w_in[i * HDIM + t], acc0);
        acc1 = fmaf(xv, w_in[i * HDIM + t + 256], acc1);
        acc2 = fmaf(xv, w_in[i * HDIM + t + 512], acc2);
    }
    h[(size_t)b * HDIM + t] = acc0;
    h[(size_t)b * HDIM + t + 256] = acc1;
    h[(size_t)b * HDIM + t + 512] = acc2;

    float s = acc0 + acc1 + acc2;
    float q = acc0 * acc0 + acc1 * acc1 + acc2 * acc2;
#pragma unroll
    for (int off = 32; off > 0; off >>= 1) { s += __shfl_down(s, off); q += __shfl_down(q, off); }
    const int wid = t >> 6, lane = t & 63;
    if (lane == 0) { rbuf[wid] = s; rbuf[4 + wid] = q; }
    __syncthreads();
    s = rbuf[0] + rbuf[1] + rbuf[2] + rbuf[3];
    q = rbuf[4] + rbuf[5] + rbuf[6] + rbuf[7];
    const float mu = s * (1.f / HDIM);
    const float var = q * (1.f / HDIM) - mu * mu;
    const float rsig = rsqrtf(var + 1e-5f);

    hnT[(size_t)(t)       * BDIM + b] = (acc0 - mu) * rsig * lng[t] + lnb[t];
    hnT[(size_t)(t + 256) * BDIM + b] = (acc1 - mu) * rsig * lng[t + 256] + lnb[t + 256];
    hnT[(size_t)(t + 512) * BDIM + b] = (acc2 - mu) * rsig * lng[t + 512] + lnb[t + 512];
}

// ---------------------------------------------------------------------------
// Kernel 1 (per layer): fused triple "matmul" partials over a k-slot.
// All staging via global_load_lds (no staging VGPRs -> no spills).
// Grid: (24 spatial, 10 slots) = 240 blocks. Slots 0..7: 80k, 8..9: 64k.
// ---------------------------------------------------------------------------
__global__ void layer_mm_k(
    const float* __restrict__ hnT,   // [k][b]  (768 x 256)
    const float* __restrict__ twT,   // trop_w^T : [k][o]
    const float* __restrict__ cwp,   // cls_w : [k][o]
    const float* __restrict__ gwp,   // gate_w: [k][o]
    float* __restrict__ p_trop, float* __restrict__ p_cls, float* __restrict__ p_gate)
{
    __shared__ float hn_s[CHK][TR];   // unpadded (required by global_load_lds)
    __shared__ float wt_s[CHK][TC];
    __shared__ float wc_s[CHK][TC];
    __shared__ float wg_s[CHK][TC];

    const int tid = threadIdx.x;
    const int sp = blockIdx.x;             // 0..23
    const int slot = blockIdx.y;           // 0..9
    const int col0 = (sp % 12) * TC;
    const int row0 = (sp / 12) * TR;
    int k0, nch;
    if (slot < 8) { k0 = slot * 80; nch = 5; }
    else          { k0 = 640 + (slot - 8) * 64; nch = 4; }

    const int wave = tid >> 6, lane = tid & 63;
    const int tx = tid & 15, ty = tid >> 4;
    const int r0 = ty * 8, c0 = tx * 4;

    // staging source offsets
    const int hk = (lane >> 5);            // 0/1 within instr pair
    const int hcol = (lane & 31) * 4;      // 0..124
    const int wk = wave * 4 + (lane >> 4); // k row for weight stage
    const int wcol = (lane & 15) * 4;      // 0..60

    float t_acc[8][4], c_acc[8][4], g_acc[8][4];
#pragma unroll
    for (int i = 0; i < 8; ++i)
#pragma unroll
        for (int j = 0; j < 4; ++j) { t_acc[i][j] = -1e30f; c_acc[i][j] = 0.f; g_acc[i][j] = 0.f; }

    for (int c = 0; c < nch; ++c) {
        const int kb = k0 + c * CHK;
        // hn: 2 instrs/wave, each covers 2 k-rows of 128 floats
        {
            const int j0 = wave * 2;       // 0,2,4,6
            gload_lds16(hnT + (size_t)(kb + 2 * j0 + hk) * BDIM + row0 + hcol, &hn_s[2 * j0][0]);
            gload_lds16(hnT + (size_t)(kb + 2 * j0 + 2 + hk) * BDIM + row0 + hcol, &hn_s[2 * j0 + 2][0]);
            // weights: 1 instr/wave each, covers 4 k-rows of 64 floats
            gload_lds16(twT + (size_t)(kb + wk) * HDIM + col0 + wcol, &wt_s[wave * 4][0]);
            gload_lds16(cwp + (size_t)(kb + wk) * HDIM + col0 + wcol, &wc_s[wave * 4][0]);
            gload_lds16(gwp + (size_t)(kb + wk) * HDIM + col0 + wcol, &wg_s[wave * 4][0]);
        }
        __builtin_amdgcn_s_waitcnt(0);     // drain global_load_lds
        __syncthreads();
#pragma unroll
        for (int k = 0; k < CHK; ++k) {
            const float4 h0 = *(const float4*)&hn_s[k][r0];
            const float4 h1 = *(const float4*)&hn_s[k][r0 + 4];
            const float4 wt = *(const float4*)&wt_s[k][c0];
            const float4 wc = *(const float4*)&wc_s[k][c0];
            const float4 wg = *(const float4*)&wg_s[k][c0];
            const float hf[8] = {h0.x, h0.y, h0.z, h0.w, h1.x, h1.y, h1.z, h1.w};
            const float wtf[4] = {wt.x, wt.y, wt.z, wt.w};
            const float wcf[4] = {wc.x, wc.y, wc.z, wc.w};
            const float wgf[4] = {wg.x, wg.y, wg.z, wg.w};
#pragma unroll
            for (int i = 0; i < 8; ++i) {
#pragma unroll
                for (int j = 0; j < 4; ++j) {
                    t_acc[i][j] = fmaxf(t_acc[i][j], hf[i] + wtf[j]);
                    c_acc[i][j] = fmaf(hf[i], wcf[j], c_acc[i][j]);
                    g_acc[i][j] = fmaf(hf[i], wgf[j], g_acc[i][j]);
                }
            }
        }
        __syncthreads();
    }

    const size_t base = (size_t)slot * BDIM * HDIM;
#pragma unroll
    for (int i = 0; i < 8; ++i) {
        const size_t off = base + (size_t)(row0 + r0 + i) * HDIM + col0 + c0;
        *(float4*)(p_trop + off) = make_float4(t_acc[i][0], t_acc[i][1], t_acc[i][2], t_acc[i][3]);
        *(float4*)(p_cls + off)  = make_float4(c_acc[i][0], c_acc[i][1], c_acc[i][2], c_acc[i][3]);
        *(float4*)(p_gate + off) = make_float4(g_acc[i][0], g_acc[i][1], g_acc[i][2], g_acc[i][3]);
    }
}

// ---------------------------------------------------------------------------
// Kernel 2 (per layer): reduce slot partials, LF activation, gelu, gate,
// residual, then LN -> hnT for next layer (or final LN + head -> out).
// 768 threads, one block per row.
// ---------------------------------------------------------------------------
__global__ __launch_bounds__(768) void combine_k(
    const float* __restrict__ p_trop, const float* __restrict__ p_cls, const float* __restrict__ p_gate,
    const float* __restrict__ trop_b,
    const float* __restrict__ amax, const float* __restrict__ bmax,
    const float* __restrict__ amin, const float* __restrict__ bmin,
    const float* __restrict__ alpha,
    const float* __restrict__ gate_b, const float* __restrict__ cls_b,
    float* __restrict__ h,
    const float* __restrict__ lng, const float* __restrict__ lnb,
    float* __restrict__ hnT,
    const float* __restrict__ head_w, const float* __restrict__ head_b,
    float* __restrict__ out, const int is_last)
{
    const int b = blockIdx.x;
    const int o = threadIdx.x;         // 0..767
    __shared__ float rbuf[12], qbuf[12];

    const size_t base = (size_t)b * HDIM + o;
    float tm = -1e30f, cs = 0.f, gs = 0.f;
#pragma unroll
    for (int k = 0; k < KSPLIT; ++k) {
        const size_t idx = (size_t)k * BDIM * HDIM + base;
        tm = fmaxf(tm, p_trop[idx]);
        cs += p_cls[idx];
        gs += p_gate[idx];
    }
    const float tv = tm + trop_b[o];
    float fmx = -1e30f, fmn = 1e30f;
#pragma unroll
    for (int p = 0; p < PDIM; ++p) {
        fmx = fmaxf(fmx, fmaf(tv, amax[o * PDIM + p], bmax[o * PDIM + p]));
        fmn = fminf(fmn, fmaf(tv, amin[o * PDIM + p], bmin[o * PDIM + p]));
    }
    const float a = sigmoidf_(alpha[o]);
    const float trop_out = a * fmx + (1.f - a) * fmn;
    const float cls_out = geluf_(cs + cls_b[o]);
    const float g = sigmoidf_(gs + gate_b[o]);
    const float val = h[base] + g * trop_out + (1.f - g) * cls_out;
    h[base] = val;

    float s = val, q = val * val;
#pragma unroll
    for (int off = 32; off > 0; off >>= 1) { s += __shfl_down(s, off); q += __shfl_down(q, off); }
    const int wid = o >> 6, lane = o & 63;
    if (lane == 0) { rbuf[wid] = s; qbuf[wid] = q; }
    __syncthreads();
    s = 0.f; q = 0.f;
#pragma unroll
    for (int w = 0; w < 12; ++w) { s += rbuf[w]; q += qbuf[w]; }
    const float mu = s * (1.f / HDIM);
    const float var = q * (1.f / HDIM) - mu * mu;
    const float rsig = rsqrtf(var + 1e-5f);
    const float ln_v = (val - mu) * rsig * lng[o] + lnb[o];

    if (!is_last) {
        hnT[(size_t)o * BDIM + b] = ln_v;
    } else {
        float part = ln_v * head_w[o];
#pragma unroll
        for (int off = 32; off > 0; off >>= 1) part += __shfl_down(part, off);
        __syncthreads();
        if (lane == 0) rbuf[wid] = part;
        __syncthreads();
        if (o == 0) {
            float r = head_b[0];
#pragma unroll
            for (int w = 0; w < 12; ++w) r += rbuf[w];
            out[b] = r;
        }
    }
}

// ---------------------------------------------------------------------------
extern "C" void kernel_launch(void* const* d_in, const int* in_sizes, int n_in,
                              void* d_out, int out_size, void* d_ws, size_t ws_size,
                              hipStream_t stream)
{
    const float* x       = (const float*)d_in[0];
    const float* w_in    = (const float*)d_in[1];
    const float* b_in    = (const float*)d_in[2];
    const float* ln_g    = (const float*)d_in[3];
    const float* ln_b    = (const float*)d_in[4];
    const float* trop_w  = (const float*)d_in[5];
    const float* trop_b  = (const float*)d_in[6];
    const float* lf_amax = (const float*)d_in[7];
    const float* lf_bmax = (const float*)d_in[8];
    const float* lf_amin = (const float*)d_in[9];
    const float* lf_bmin = (const float*)d_in[10];
    const float* lf_alpha= (const float*)d_in[11];
    const float* gate_w  = (const float*)d_in[12];
    const float* gate_b  = (const float*)d_in[13];
    const float* cls_w   = (const float*)d_in[14];
    const float* cls_b   = (const float*)d_in[15];
    const float* out_g   = (const float*)d_in[16];
    const float* out_b   = (const float*)d_in[17];
    const float* head_w  = (const float*)d_in[18];
    const float* head_b  = (const float*)d_in[19];
    float* out = (float*)d_out;

    const size_t NBH = (size_t)BDIM * HDIM;    // 196608
    const size_t WSZ = (size_t)HDIM * HDIM;    // 589824
    float* ws = (float*)d_ws;
    float* h      = ws;                        // NBH
    float* hnT    = ws + NBH;                  // NBH (transposed [k][b])
    float* twT    = ws + 2 * NBH;              // L*WSZ
    float* p_trop = twT + (size_t)NLAYERS * WSZ;   // KSPLIT*NBH
    float* p_cls  = p_trop + (size_t)KSPLIT * NBH;
    float* p_gate = p_cls + (size_t)KSPLIT * NBH;
    // total ~34.6 MB

    transpose_w_k<<<dim3(12, 12, NLAYERS), 256, 0, stream>>>(trop_w, twT);
    input_ln_k<<<BDIM, 256, 0, stream>>>(x, w_in, b_in, ln_g, ln_b, h, hnT);

    for (int l = 0; l < NLAYERS; ++l) {
        layer_mm_k<<<dim3(24, KSPLIT), 256, 0, stream>>>(
            hnT,
            twT + (size_t)l * WSZ,
            cls_w + (size_t)l * WSZ,
            gate_w + (size_t)l * WSZ,
            p_trop, p_cls, p_gate);

        const int is_last = (l == NLAYERS - 1);
        combine_k<<<BDIM, 768, 0, stream>>>(
            p_trop, p_cls, p_gate,
            trop_b + (size_t)l * HDIM,
            lf_amax + (size_t)l * HDIM * PDIM, lf_bmax + (size_t)l * HDIM * PDIM,
            lf_amin + (size_t)l * HDIM * PDIM, lf_bmin + (size_t)l * HDIM * PDIM,
            lf_alpha + (size_t)l * HDIM,
            gate_b + (size_t)l * HDIM, cls_b + (size_t)l * HDIM,
            h,
            is_last ? out_g : ln_g + (size_t)(l + 1) * HDIM,
            is_last ? out_b : ln_b + (size_t)(l + 1) * HDIM,
            hnT, head_w, head_b, out, is_last);
    }
}

// Round 4
// 251.157 us; speedup vs baseline: 4.9790x; 4.9790x over previous
//
#include <hip/hip_runtime.h>
#include <math.h>

#define HDIM 768
#define BDIM 256
#define INDIM 64
#define NLAYERS 4
#define PDIM 8
#define KSPLIT 10     // 8 slots x 80k + 2 slots x 64k = 768
#define CHK 16        // k per LDS chunk
#define TR 128        // rows per block tile
#define TC 64         // cols per block tile

__device__ __forceinline__ float sigmoidf_(float x) { return 1.f / (1.f + expf(-x)); }
__device__ __forceinline__ float geluf_(float x) { return 0.5f * x * (1.f + erff(x * 0.70710678118654752f)); }

// async global->LDS, 16B/lane, lane i lands at ldsbase + i*16 (wave-uniform base)
__device__ __forceinline__ void gload_lds16(const float* g, float* l) {
    __builtin_amdgcn_global_load_lds((const __attribute__((address_space(1))) void*)g,
                                     (__attribute__((address_space(3))) void*)l, 16, 0, 0);
}

// ---------------------------------------------------------------------------
// Transpose trop_w [L][o][i] -> twT [L][i][o].  grid (12,12,L), 256 thr.
// ---------------------------------------------------------------------------
__global__ __launch_bounds__(256) void transpose_w_k(const float* __restrict__ src,
                                                     float* __restrict__ dst)
{
    __shared__ float tile[64][65];
    const int l = blockIdx.z;
    const int o0 = blockIdx.x * 64;
    const int i0 = blockIdx.y * 64;
    const int c = threadIdx.x & 63;
    const int r4 = threadIdx.x >> 6;
    const float* s = src + (size_t)l * HDIM * HDIM;
    float* d = dst + (size_t)l * HDIM * HDIM;
#pragma unroll
    for (int it = 0; it < 16; ++it) {
        const int r = it * 4 + r4;
        tile[r][c] = s[(size_t)(o0 + r) * HDIM + i0 + c];
    }
    __syncthreads();
#pragma unroll
    for (int it = 0; it < 16; ++it) {
        const int r = it * 4 + r4;
        d[(size_t)(i0 + r) * HDIM + o0 + c] = tile[c][r];
    }
}

// ---------------------------------------------------------------------------
// Kernel 0: h = x @ w_in + b_in, then LN(layer 0) -> hnT ([k][b] transposed).
// ---------------------------------------------------------------------------
__global__ __launch_bounds__(256) void input_ln_k(
    const float* __restrict__ x, const float* __restrict__ w_in,
    const float* __restrict__ b_in,
    const float* __restrict__ lng, const float* __restrict__ lnb,
    float* __restrict__ h, float* __restrict__ hnT)
{
    const int b = blockIdx.x;
    const int t = threadIdx.x;
    __shared__ float xs[INDIM];
    __shared__ float rbuf[8];
    if (t < INDIM) xs[t] = x[b * INDIM + t];
    __syncthreads();

    float acc0 = b_in[t], acc1 = b_in[t + 256], acc2 = b_in[t + 512];
#pragma unroll 8
    for (int i = 0; i < INDIM; ++i) {
        const float xv = xs[i];
        acc0 = fmaf(xv, w_in[i * HDIM + t], acc0);
        acc1 = fmaf(xv, w_in[i * HDIM + t + 256], acc1);
        acc2 = fmaf(xv, w_in[i * HDIM + t + 512], acc2);
    }
    h[(size_t)b * HDIM + t] = acc0;
    h[(size_t)b * HDIM + t + 256] = acc1;
    h[(size_t)b * HDIM + t + 512] = acc2;

    float s = acc0 + acc1 + acc2;
    float q = acc0 * acc0 + acc1 * acc1 + acc2 * acc2;
#pragma unroll
    for (int off = 32; off > 0; off >>= 1) { s += __shfl_down(s, off); q += __shfl_down(q, off); }
    const int wid = t >> 6, lane = t & 63;
    if (lane == 0) { rbuf[wid] = s; rbuf[4 + wid] = q; }
    __syncthreads();
    s = rbuf[0] + rbuf[1] + rbuf[2] + rbuf[3];
    q = rbuf[4] + rbuf[5] + rbuf[6] + rbuf[7];
    const float mu = s * (1.f / HDIM);
    const float var = q * (1.f / HDIM) - mu * mu;
    const float rsig = rsqrtf(var + 1e-5f);

    hnT[(size_t)(t)       * BDIM + b] = (acc0 - mu) * rsig * lng[t] + lnb[t];
    hnT[(size_t)(t + 256) * BDIM + b] = (acc1 - mu) * rsig * lng[t + 256] + lnb[t + 256];
    hnT[(size_t)(t + 512) * BDIM + b] = (acc2 - mu) * rsig * lng[t + 512] + lnb[t + 512];
}

// ---------------------------------------------------------------------------
// Kernel 1 (per layer): fused triple "matmul" partials over a k-slot.
// global_load_lds staging (no staging VGPRs), DOUBLE-BUFFERED so the DMA for
// chunk c+1 overlaps compute of chunk c.  __launch_bounds__(256,1): the 96
// accumulators + temps need ~150 VGPRs — defaults cap at 64 and spill
// catastrophically (R2/R3: 650 MB scratch traffic).  1 block/CU is fine:
// grid 240 blocks, all co-resident, ILP + dbuf hide latency.
// ---------------------------------------------------------------------------
__global__ __launch_bounds__(256, 1) void layer_mm_k(
    const float* __restrict__ hnT,   // [k][b]  (768 x 256)
    const float* __restrict__ twT,   // trop_w^T : [k][o]
    const float* __restrict__ cwp,   // cls_w : [k][o]
    const float* __restrict__ gwp,   // gate_w: [k][o]
    float* __restrict__ p_trop, float* __restrict__ p_cls, float* __restrict__ p_gate)
{
    __shared__ float hn_s[2][CHK][TR];   // unpadded (required by global_load_lds)
    __shared__ float wt_s[2][CHK][TC];
    __shared__ float wc_s[2][CHK][TC];
    __shared__ float wg_s[2][CHK][TC];   // total 40 KB

    const int tid = threadIdx.x;
    const int sp = blockIdx.x;             // 0..23
    const int slot = blockIdx.y;           // 0..9
    const int col0 = (sp % 12) * TC;
    const int row0 = (sp / 12) * TR;
    int k0, nch;
    if (slot < 8) { k0 = slot * 80; nch = 5; }
    else          { k0 = 640 + (slot - 8) * 64; nch = 4; }

    const int wave = tid >> 6, lane = tid & 63;
    const int tx = tid & 15, ty = tid >> 4;
    const int r0 = ty * 8, c0 = tx * 4;

    // staging source offsets
    const int hk = (lane >> 5);            // 0/1 within instr pair
    const int hcol = (lane & 31) * 4;      // 0..124
    const int wk = wave * 4 + (lane >> 4); // k row for weight stage
    const int wcol = (lane & 15) * 4;      // 0..60

    float t_acc[8][4], c_acc[8][4], g_acc[8][4];
#pragma unroll
    for (int i = 0; i < 8; ++i)
#pragma unroll
        for (int j = 0; j < 4; ++j) { t_acc[i][j] = -1e30f; c_acc[i][j] = 0.f; g_acc[i][j] = 0.f; }

    // stage chunk kb into buffer buf (5 global_load_lds instrs per wave)
    #define STAGE(buf, kb)                                                                        \
    {                                                                                             \
        const int j0 = wave * 4;                                                                  \
        gload_lds16(hnT + (size_t)((kb) + j0 + hk) * BDIM + row0 + hcol, &hn_s[buf][j0][0]);      \
        gload_lds16(hnT + (size_t)((kb) + j0 + 2 + hk) * BDIM + row0 + hcol, &hn_s[buf][j0 + 2][0]); \
        gload_lds16(twT + (size_t)((kb) + wk) * HDIM + col0 + wcol, &wt_s[buf][wave * 4][0]);     \
        gload_lds16(cwp + (size_t)((kb) + wk) * HDIM + col0 + wcol, &wc_s[buf][wave * 4][0]);     \
        gload_lds16(gwp + (size_t)((kb) + wk) * HDIM + col0 + wcol, &wg_s[buf][wave * 4][0]);     \
    }

    STAGE(0, k0);
    __builtin_amdgcn_s_waitcnt(0);
    __syncthreads();

    for (int c = 0; c < nch; ++c) {
        const int buf = c & 1;
        if (c + 1 < nch) STAGE(1 - buf, k0 + (c + 1) * CHK);
#pragma unroll
        for (int k = 0; k < CHK; ++k) {
            const float4 h0 = *(const float4*)&hn_s[buf][k][r0];
            const float4 h1 = *(const float4*)&hn_s[buf][k][r0 + 4];
            const float4 wt = *(const float4*)&wt_s[buf][k][c0];
            const float4 wc = *(const float4*)&wc_s[buf][k][c0];
            const float4 wg = *(const float4*)&wg_s[buf][k][c0];
            const float hf[8] = {h0.x, h0.y, h0.z, h0.w, h1.x, h1.y, h1.z, h1.w};
            const float wtf[4] = {wt.x, wt.y, wt.z, wt.w};
            const float wcf[4] = {wc.x, wc.y, wc.z, wc.w};
            const float wgf[4] = {wg.x, wg.y, wg.z, wg.w};
#pragma unroll
            for (int i = 0; i < 8; ++i) {
#pragma unroll
                for (int j = 0; j < 4; ++j) {
                    t_acc[i][j] = fmaxf(t_acc[i][j], hf[i] + wtf[j]);
                    c_acc[i][j] = fmaf(hf[i], wcf[j], c_acc[i][j]);
                    g_acc[i][j] = fmaf(hf[i], wgf[j], g_acc[i][j]);
                }
            }
        }
        __builtin_amdgcn_s_waitcnt(0);     // drain next-chunk DMA (long since landed)
        __syncthreads();
    }
    #undef STAGE

    const size_t base = (size_t)slot * BDIM * HDIM;
#pragma unroll
    for (int i = 0; i < 8; ++i) {
        const size_t off = base + (size_t)(row0 + r0 + i) * HDIM + col0 + c0;
        *(float4*)(p_trop + off) = make_float4(t_acc[i][0], t_acc[i][1], t_acc[i][2], t_acc[i][3]);
        *(float4*)(p_cls + off)  = make_float4(c_acc[i][0], c_acc[i][1], c_acc[i][2], c_acc[i][3]);
        *(float4*)(p_gate + off) = make_float4(g_acc[i][0], g_acc[i][1], g_acc[i][2], g_acc[i][3]);
    }
}

// ---------------------------------------------------------------------------
// Kernel 2 (per layer): reduce slot partials, LF activation, gelu, gate,
// residual, then LN -> hnT for next layer (or final LN + head -> out).
// 768 threads, one block per row.
// ---------------------------------------------------------------------------
__global__ __launch_bounds__(768) void combine_k(
    const float* __restrict__ p_trop, const float* __restrict__ p_cls, const float* __restrict__ p_gate,
    const float* __restrict__ trop_b,
    const float* __restrict__ amax, const float* __restrict__ bmax,
    const float* __restrict__ amin, const float* __restrict__ bmin,
    const float* __restrict__ alpha,
    const float* __restrict__ gate_b, const float* __restrict__ cls_b,
    float* __restrict__ h,
    const float* __restrict__ lng, const float* __restrict__ lnb,
    float* __restrict__ hnT,
    const float* __restrict__ head_w, const float* __restrict__ head_b,
    float* __restrict__ out, const int is_last)
{
    const int b = blockIdx.x;
    const int o = threadIdx.x;         // 0..767
    __shared__ float rbuf[12], qbuf[12];

    const size_t base = (size_t)b * HDIM + o;
    float tm = -1e30f, cs = 0.f, gs = 0.f;
#pragma unroll
    for (int k = 0; k < KSPLIT; ++k) {
        const size_t idx = (size_t)k * BDIM * HDIM + base;
        tm = fmaxf(tm, p_trop[idx]);
        cs += p_cls[idx];
        gs += p_gate[idx];
    }
    const float tv = tm + trop_b[o];
    float fmx = -1e30f, fmn = 1e30f;
#pragma unroll
    for (int p = 0; p < PDIM; ++p) {
        fmx = fmaxf(fmx, fmaf(tv, amax[o * PDIM + p], bmax[o * PDIM + p]));
        fmn = fminf(fmn, fmaf(tv, amin[o * PDIM + p], bmin[o * PDIM + p]));
    }
    const float a = sigmoidf_(alpha[o]);
    const float trop_out = a * fmx + (1.f - a) * fmn;
    const float cls_out = geluf_(cs + cls_b[o]);
    const float g = sigmoidf_(gs + gate_b[o]);
    const float val = h[base] + g * trop_out + (1.f - g) * cls_out;
    h[base] = val;

    float s = val, q = val * val;
#pragma unroll
    for (int off = 32; off > 0; off >>= 1) { s += __shfl_down(s, off); q += __shfl_down(q, off); }
    const int wid = o >> 6, lane = o & 63;
    if (lane == 0) { rbuf[wid] = s; qbuf[wid] = q; }
    __syncthreads();
    s = 0.f; q = 0.f;
#pragma unroll
    for (int w = 0; w < 12; ++w) { s += rbuf[w]; q += qbuf[w]; }
    const float mu = s * (1.f / HDIM);
    const float var = q * (1.f / HDIM) - mu * mu;
    const float rsig = rsqrtf(var + 1e-5f);
    const float ln_v = (val - mu) * rsig * lng[o] + lnb[o];

    if (!is_last) {
        hnT[(size_t)o * BDIM + b] = ln_v;
    } else {
        float part = ln_v * head_w[o];
#pragma unroll
        for (int off = 32; off > 0; off >>= 1) part += __shfl_down(part, off);
        __syncthreads();
        if (lane == 0) rbuf[wid] = part;
        __syncthreads();
        if (o == 0) {
            float r = head_b[0];
#pragma unroll
            for (int w = 0; w < 12; ++w) r += rbuf[w];
            out[b] = r;
        }
    }
}

// ---------------------------------------------------------------------------
extern "C" void kernel_launch(void* const* d_in, const int* in_sizes, int n_in,
                              void* d_out, int out_size, void* d_ws, size_t ws_size,
                              hipStream_t stream)
{
    const float* x       = (const float*)d_in[0];
    const float* w_in    = (const float*)d_in[1];
    const float* b_in    = (const float*)d_in[2];
    const float* ln_g    = (const float*)d_in[3];
    const float* ln_b    = (const float*)d_in[4];
    const float* trop_w  = (const float*)d_in[5];
    const float* trop_b  = (const float*)d_in[6];
    const float* lf_amax = (const float*)d_in[7];
    const float* lf_bmax = (const float*)d_in[8];
    const float* lf_amin = (const float*)d_in[9];
    const float* lf_bmin = (const float*)d_in[10];
    const float* lf_alpha= (const float*)d_in[11];
    const float* gate_w  = (const float*)d_in[12];
    const float* gate_b  = (const float*)d_in[13];
    const float* cls_w   = (const float*)d_in[14];
    const float* cls_b   = (const float*)d_in[15];
    const float* out_g   = (const float*)d_in[16];
    const float* out_b   = (const float*)d_in[17];
    const float* head_w  = (const float*)d_in[18];
    const float* head_b  = (const float*)d_in[19];
    float* out = (float*)d_out;

    const size_t NBH = (size_t)BDIM * HDIM;    // 196608
    const size_t WSZ = (size_t)HDIM * HDIM;    // 589824
    float* ws = (float*)d_ws;
    float* h      = ws;                        // NBH
    float* hnT    = ws + NBH;                  // NBH (transposed [k][b])
    float* twT    = ws + 2 * NBH;              // L*WSZ
    float* p_trop = twT + (size_t)NLAYERS * WSZ;   // KSPLIT*NBH
    float* p_cls  = p_trop + (size_t)KSPLIT * NBH;
    float* p_gate = p_cls + (size_t)KSPLIT * NBH;
    // total ~34.6 MB

    transpose_w_k<<<dim3(12, 12, NLAYERS), 256, 0, stream>>>(trop_w, twT);
    input_ln_k<<<BDIM, 256, 0, stream>>>(x, w_in, b_in, ln_g, ln_b, h, hnT);

    for (int l = 0; l < NLAYERS; ++l) {
        layer_mm_k<<<dim3(24, KSPLIT), 256, 0, stream>>>(
            hnT,
            twT + (size_t)l * WSZ,
            cls_w + (size_t)l * WSZ,
            gate_w + (size_t)l * WSZ,
            p_trop, p_cls, p_gate);

        const int is_last = (l == NLAYERS - 1);
        combine_k<<<BDIM, 768, 0, stream>>>(
            p_trop, p_cls, p_gate,
            trop_b + (size_t)l * HDIM,
            lf_amax + (size_t)l * HDIM * PDIM, lf_bmax + (size_t)l * HDIM * PDIM,
            lf_amin + (size_t)l * HDIM * PDIM, lf_bmin + (size_t)l * HDIM * PDIM,
            lf_alpha + (size_t)l * HDIM,
            gate_b + (size_t)l * HDIM, cls_b + (size_t)l * HDIM,
            h,
            is_last ? out_g : ln_g + (size_t)(l + 1) * HDIM,
            is_last ? out_b : ln_b + (size_t)(l + 1) * HDIM,
            hnT, head_w, head_b, out, is_last);
    }
}